// Round 9
// baseline (508.239 us; speedup 1.0000x reference)
//
#include <hip/hip_runtime.h>
#include <hip/hip_fp16.h>

#define NN 32      // nodes
#define FF 64      // GAT out features
#define HH 128     // LSTM hidden
#define G4 512     // 4*H
#define BB 32      // batch
#define TT 512     // time steps
#define ET 128     // 96 edges + 32 self loops
#define NPOS (BB*TT)

__device__ __forceinline__ float frcp(float x) { return __builtin_amdgcn_rcpf(x); }

// ---------------- prep: fold GAT linear into LSTM input weights + Wt transpose ----------------
// R20 weight layout (f16): thread tid = r*4+kq. Wt16[tid*128 + P*8 + g*2 + e] =
//   f16(W_hh[(kq*32 + 2P + e)][g*128 + r]),  P=0..15 k-pair, g gate, e parity.
__global__ __launch_bounds__(512) void prep_kernel(const float* __restrict__ w_gat,
                                                   const float* __restrict__ b_gat,
                                                   const float* __restrict__ W_ih,
                                                   const float* __restrict__ W_hh,
                                                   float* __restrict__ W_eff,
                                                   float* __restrict__ biasp,
                                                   float* __restrict__ Wt) {
  int j = threadIdx.x;
  int n = blockIdx.x;
  float accw = 0.f, accb = 0.f;
#pragma unroll 8
  for (int f = 0; f < FF; ++f) {
    float wv = W_ih[(n * FF + f) * G4 + j];
    accw = fmaf(w_gat[f], wv, accw);
    accb = fmaf(b_gat[f], wv, accb);
  }
  W_eff[n * G4 + j] = accw;
  biasp[n * G4 + j] = accb;
  __half* Wt16 = (__half*)Wt;
  int g0 = (n * G4 + j) * 4;
#pragma unroll
  for (int q = 0; q < 4; ++q) {
    int E = g0 + q;
    int tl = E >> 7, idx = E & 127;
    int r = tl >> 2, kq = tl & 3;
    int P = idx >> 3;            // k-pair 0..15
    int g = (idx >> 1) & 3;      // gate
    int e = idx & 1;             // parity within pair
    int k = kq * 32 + 2 * P + e;
    Wt16[E] = __float2half(W_hh[k * G4 + g * 128 + r]);
  }
}

// ---------------- fused: GAT+xw prologue (own batch) + R20 LSTM scan ----------------
// R21: the total-minus-lstm gap has been 104-109us in EVERY round, invariant to gatxw
// structure (R19: 4x amortization -> no change). Work arithmetic says prep+gatxw ~ 7us.
// Hypothesis: per-dispatch/serialization overhead of the 3-kernel pipeline. Test: fuse
// gatxw into the scan kernel (block b computes its own 512 xw rows -> global -> fence ->
// scan). No cross-block dep => no grid sync. Scan core is R20-verbatim (249us verified).

#define D2F(HJ, W0, W1, W2, W3) \
  "v_dot2_f32_f16 v216, v" HJ ", v" W0 ", 0\n\t" \
  "v_dot2_f32_f16 v217, v" HJ ", v" W1 ", 0\n\t" \
  "v_dot2_f32_f16 v218, v" HJ ", v" W2 ", 0\n\t" \
  "v_dot2_f32_f16 v219, v" HJ ", v" W3 ", 0\n\t"

#define D2A(HJ, W0, W1, W2, W3) \
  "v_dot2_f32_f16 v216, v" HJ ", v" W0 ", v216\n\t" \
  "v_dot2_f32_f16 v217, v" HJ ", v" W1 ", v217\n\t" \
  "v_dot2_f32_f16 v218, v" HJ ", v" W2 ", v218\n\t" \
  "v_dot2_f32_f16 v219, v" HJ ", v" W3 ", v219\n\t"

#define PHASE(XSLOT, RD, WR) \
  "ds_read_b128 v[32:35], " RD "\n\t" \
  "ds_read_b128 v[36:39], " RD " offset:16\n\t" \
  "ds_read_b128 v[40:43], " RD " offset:32\n\t" \
  "ds_read_b128 v[44:47], " RD " offset:48\n\t" \
  "s_waitcnt lgkmcnt(3)\n\t" \
  D2F("32", "64", "65", "66", "67") \
  D2A("33", "68", "69", "70", "71") \
  D2A("34", "72", "73", "74", "75") \
  D2A("35", "76", "77", "78", "79") \
  "s_waitcnt lgkmcnt(2)\n\t" \
  D2A("36", "80", "81", "82", "83") \
  D2A("37", "84", "85", "86", "87") \
  D2A("38", "88", "89", "90", "91") \
  D2A("39", "92", "93", "94", "95") \
  "s_waitcnt lgkmcnt(1)\n\t" \
  D2A("40", "96", "97", "98", "99") \
  D2A("41", "100", "101", "102", "103") \
  D2A("42", "104", "105", "106", "107") \
  D2A("43", "108", "109", "110", "111") \
  "s_waitcnt lgkmcnt(0)\n\t" \
  D2A("44", "112", "113", "114", "115") \
  D2A("45", "116", "117", "118", "119") \
  D2A("46", "120", "121", "122", "123") \
  D2A("47", "124", "125", "126", "127") \
  "v_add_f32_dpp v216, v216, v216 quad_perm:[1,0,3,2] row_mask:0xf bank_mask:0xf\n\t" \
  "v_add_f32_dpp v217, v217, v217 quad_perm:[1,0,3,2] row_mask:0xf bank_mask:0xf\n\t" \
  "v_add_f32_dpp v218, v218, v218 quad_perm:[1,0,3,2] row_mask:0xf bank_mask:0xf\n\t" \
  "v_add_f32_dpp v219, v219, v219 quad_perm:[1,0,3,2] row_mask:0xf bank_mask:0xf\n\t" \
  "v_add_f32_dpp v216, v216, v216 quad_perm:[2,3,0,1] row_mask:0xf bank_mask:0xf\n\t" \
  "v_add_f32_dpp v217, v217, v217 quad_perm:[2,3,0,1] row_mask:0xf bank_mask:0xf\n\t" \
  "v_add_f32_dpp v218, v218, v218 quad_perm:[2,3,0,1] row_mask:0xf bank_mask:0xf\n\t" \
  "v_add_f32_dpp v219, v219, v219 quad_perm:[2,3,0,1] row_mask:0xf bank_mask:0xf\n\t" \
  "v_cndmask_b32 v208, v216, v217, s[22:23]\n\t" \
  "v_cndmask_b32 v209, v218, v219, s[22:23]\n\t" \
  "v_cndmask_b32 v208, v208, v209, s[24:25]\n\t" \
  "s_waitcnt vmcnt(3)\n\t" \
  "v_mov_b32 v215, " XSLOT "\n\t" \
  "global_load_dword " XSLOT ", v194, %[xwb]\n\t" \
  "v_add_u32 v194, 0x800, v194\n\t" \
  "v_add_f32 v208, v208, v215\n\t" \
  "v_mul_f32 v209, v200, v208\n\t" \
  "v_exp_f32 v209, v209\n\t" \
  "s_nop 0\n\t" \
  "v_add_f32 v209, 1.0, v209\n\t" \
  "v_rcp_f32 v209, v209\n\t" \
  "s_nop 0\n\t" \
  "v_fma_f32 v210, v201, v209, v202\n\t" \
  "s_nop 1\n\t" \
  "v_add_f32_dpp v211, v210, v203 quad_perm:[0,0,0,0] row_mask:0xf bank_mask:0xf\n\t" \
  "v_add_f32_dpp v212, v210, v203 quad_perm:[1,1,1,1] row_mask:0xf bank_mask:0xf\n\t" \
  "v_add_f32_dpp v213, v210, v203 quad_perm:[2,2,2,2] row_mask:0xf bank_mask:0xf\n\t" \
  "v_add_f32_dpp v214, v210, v203 quad_perm:[3,3,3,3] row_mask:0xf bank_mask:0xf\n\t" \
  "v_mul_f32 v211, v211, v213\n\t" \
  "v_fma_f32 v199, v212, v199, v211\n\t" \
  "v_mul_f32 v209, 0x4038aa3b, v199\n\t" \
  "v_exp_f32 v209, v209\n\t" \
  "s_nop 0\n\t" \
  "v_add_f32 v209, 1.0, v209\n\t" \
  "v_rcp_f32 v209, v209\n\t" \
  "s_nop 0\n\t" \
  "v_fma_f32 v209, -2.0, v209, 1.0\n\t" \
  "v_mul_f32 v209, v214, v209\n\t" \
  "v_cvt_f16_f32 v209, v209\n\t" \
  "ds_write_b16 " WR ", v209\n\t" \
  "s_waitcnt lgkmcnt(0)\n\t" \
  "s_barrier\n\t"

__global__ __launch_bounds__(512, 2) void fused_kernel(const float* __restrict__ x_seq,
                                                       const int* __restrict__ ei,
                                                       const float* __restrict__ w_gat,
                                                       const float* __restrict__ att_src,
                                                       const float* __restrict__ att_dst,
                                                       const float* __restrict__ b_ih,
                                                       const float* __restrict__ b_hh,
                                                       const float* __restrict__ W_eff,
                                                       const float* __restrict__ biasp,
                                                       const float* __restrict__ Wt,
                                                       const float* __restrict__ W_fc,
                                                       const float* __restrict__ b_fc,
                                                       float* __restrict__ xw,
                                                       float* __restrict__ out) {
  __shared__ int srt[ET];
  __shared__ int offs[NN + 1];
  __shared__ int cnt[NN];
  __shared__ float xs[32 * NN];   // 1024: one 32-position round
  __shared__ float sl[32 * NN];   // 1024
  __shared__ float scal_sh[2];
  __shared__ __align__(16) float hlds[160];  // f16 h: hA bytes [0,320), hB [320,640)
  int tid = threadIdx.x;
  int b = blockIdx.x;
  float* xwb_w = xw + (size_t)b * TT * G4;

  // ---------- phase 1: compute this batch's xw rows (gatxw port, 1 column/thread) ----------
  float wcol[NN];
#pragma unroll
  for (int nn = 0; nn < NN; ++nn) wcol[nn] = W_eff[nn * G4 + tid];
  float bcol = b_ih[tid] + b_hh[tid];
#pragma unroll 8
  for (int nn = 0; nn < NN; ++nn) bcol += biasp[nn * G4 + tid];
  if (tid < NN) cnt[tid] = 0;
  __syncthreads();
  int es = 0, ed = 0, tk = 0;
  if (tid < ET) {
    if (tid < 96) { es = ei[tid]; ed = ei[96 + tid]; }
    else { es = tid - 96; ed = tid - 96; }
    tk = atomicAdd(&cnt[ed], 1);
  }
  __syncthreads();
  if (tid == 0) {
    offs[0] = 0;
    for (int n = 0; n < NN; ++n) offs[n + 1] = offs[n] + cnt[n];
  }
  if (tid == 1) {
    float cs = 0.f, cd = 0.f;
    for (int f = 0; f < FF; ++f) {
      cs = fmaf(w_gat[f], att_src[f], cs);
      cd = fmaf(w_gat[f], att_dst[f], cd);
    }
    scal_sh[0] = cs;
    scal_sh[1] = cd;
  }
  __syncthreads();
  if (tid < ET) srt[offs[ed] + tk] = es;
  __syncthreads();
  int n = tid & 31;
  int e0 = offs[n], e1 = offs[n + 1];
  float cs = scal_sh[0], cd = scal_sh[1];
  for (int rd = 0; rd < TT / 32; ++rd) {           // 16 rounds x 32 positions
    size_t gbase = ((size_t)b * TT + rd * 32) * NN;
    xs[tid] = x_seq[gbase + tid];
    xs[512 + tid] = x_seq[gbase + 512 + tid];
    __syncthreads();
#pragma unroll
    for (int pp2 = 0; pp2 < 2; ++pp2) {            // softmax: 2 (pos,node) per thread
      int p = (tid >> 5) + pp2 * 16;
      int base = p * 32;
      float xn = xs[base + n];
      float cdxn = cd * xn;
      float m = -3.0e38f;
      for (int e = e0; e < e1; ++e) {
        float ev = fmaf(cs, xs[base + srt[e]], cdxn);
        ev = ev > 0.f ? ev : 0.2f * ev;             // LeakyReLU(0.2)
        m = fmaxf(m, ev);
      }
      float z = 0.f, sa = 0.f;
      for (int e = e0; e < e1; ++e) {
        float xsv = xs[base + srt[e]];
        float ev = fmaf(cs, xsv, cdxn);
        ev = ev > 0.f ? ev : 0.2f * ev;
        float ex = __expf(ev - m);
        z += ex;
        sa = fmaf(ex, xsv, sa);
      }
      sl[base + n] = sa * frcp(z);
    }
    __syncthreads();
#pragma unroll 4
    for (int pp = 0; pp < 32; ++pp) {              // GEMV: column tid over 32 nodes
      const float4* sp = (const float4*)&sl[pp * 32];
      float a0 = bcol;
#pragma unroll
      for (int q = 0; q < 8; ++q) {
        float4 sv = sp[q];
        a0 = fmaf(sv.x, wcol[4 * q], a0);
        a0 = fmaf(sv.y, wcol[4 * q + 1], a0);
        a0 = fmaf(sv.z, wcol[4 * q + 2], a0);
        a0 = fmaf(sv.w, wcol[4 * q + 3], a0);
      }
      xwb_w[(size_t)(rd * 32 + pp) * G4 + tid] = a0;
    }
    __syncthreads();                               // protect xs/sl for next round
  }
  __threadfence();                                 // xw writes visible to own reads

  // ---------- phase 2: R20 LSTM scan (verbatim) ----------
  int r = tid >> 2, kq = tid & 3;
  if (tid < 160) hlds[tid] = 0.f;                  // f16 zeros
  const float* xwb = xw + (size_t)b * TT * G4;
  unsigned xoff0 = (unsigned)((kq * 128 + r) * 4); // t=0 (xw is f32)
  unsigned wtoff = (unsigned)(tid * 256);          // 128 f16 = 256 B per thread
  unsigned lbase = (unsigned)(uintptr_t)&hlds[0];  // LDS aperture is 4GB-aligned
  unsigned rda = lbase + (unsigned)(kq * 80);      // quarter kq: 32 f16 = 64B (stripe 40 f16)
  unsigned rdb = rda + 320;
  unsigned wra = lbase + (unsigned)(((r >> 5) * 40 + (r & 31)) * 2);  // f16 element
  unsigned wrb = wra + 320;
  float kmulf = (kq == 2) ? __uint_as_float(0x4038aa3bu)   //  2*log2e
                          : __uint_as_float(0xbfb8aa3bu);  // -log2e
  float Af = (kq == 2) ? -2.f : 1.f;
  float Bf = (kq == 2) ? 1.f : 0.f;
  unsigned kqodd = kq & 1, kqhi = kq >> 1;
  __syncthreads();
  asm volatile(
    "v_mov_b32 v194, %[xo]\n\t"
    "v_mov_b32 v195, %[rda]\n\t"
    "v_mov_b32 v196, %[rdb]\n\t"
    "v_mov_b32 v197, %[wra]\n\t"
    "v_mov_b32 v198, %[wrb]\n\t"
    "v_mov_b32 v199, 0\n\t"          // c
    "v_mov_b32 v200, %[km]\n\t"      // kmul
    "v_mov_b32 v201, %[Aa]\n\t"      // A
    "v_mov_b32 v202, %[Bb]\n\t"      // B
    "v_mov_b32 v203, 0\n\t"          // zero (DPP-gather src1)
    "v_cmp_eq_u32 s[22:23], 1, %[kodd]\n\t"
    "v_cmp_eq_u32 s[24:25], 1, %[khi]\n\t"
    // x prefetch ring: t=0..3 -> v224..v227
    "global_load_dword v224, v194, %[xwb]\n\t"
    "v_add_u32 v194, 0x800, v194\n\t"
    "global_load_dword v225, v194, %[xwb]\n\t"
    "v_add_u32 v194, 0x800, v194\n\t"
    "global_load_dword v226, v194, %[xwb]\n\t"
    "v_add_u32 v194, 0x800, v194\n\t"
    "global_load_dword v227, v194, %[xwb]\n\t"
    "v_add_u32 v194, 0x800, v194\n\t"
    // 128 f16 weights -> v64..v127 (16 x dwordx4)
    "global_load_dwordx4 v[64:67], %[wto], %[wtb] offset:0\n\t"
    "global_load_dwordx4 v[68:71], %[wto], %[wtb] offset:16\n\t"
    "global_load_dwordx4 v[72:75], %[wto], %[wtb] offset:32\n\t"
    "global_load_dwordx4 v[76:79], %[wto], %[wtb] offset:48\n\t"
    "global_load_dwordx4 v[80:83], %[wto], %[wtb] offset:64\n\t"
    "global_load_dwordx4 v[84:87], %[wto], %[wtb] offset:80\n\t"
    "global_load_dwordx4 v[88:91], %[wto], %[wtb] offset:96\n\t"
    "global_load_dwordx4 v[92:95], %[wto], %[wtb] offset:112\n\t"
    "global_load_dwordx4 v[96:99], %[wto], %[wtb] offset:128\n\t"
    "global_load_dwordx4 v[100:103], %[wto], %[wtb] offset:144\n\t"
    "global_load_dwordx4 v[104:107], %[wto], %[wtb] offset:160\n\t"
    "global_load_dwordx4 v[108:111], %[wto], %[wtb] offset:176\n\t"
    "global_load_dwordx4 v[112:115], %[wto], %[wtb] offset:192\n\t"
    "global_load_dwordx4 v[116:119], %[wto], %[wtb] offset:208\n\t"
    "global_load_dwordx4 v[120:123], %[wto], %[wtb] offset:224\n\t"
    "global_load_dwordx4 v[124:127], %[wto], %[wtb] offset:240\n\t"
    "s_waitcnt vmcnt(0)\n\t"
    "s_movk_i32 s20, 0x80\n\t"    // 128 iterations x 4 phases = 512 steps
    "L_lstm_%=:\n\t"
    PHASE("v224", "v195", "v198")   // t%4==0: read A, write B
    PHASE("v225", "v196", "v197")   // t%4==1: read B, write A
    PHASE("v226", "v195", "v198")   // t%4==2: read A, write B
    PHASE("v227", "v196", "v197")   // t%4==3: read B, write A
    "s_sub_u32 s20, s20, 1\n\t"
    "s_cmp_lg_u32 s20, 0\n\t"
    "s_cbranch_scc1 L_lstm_%=\n\t"
    "s_waitcnt vmcnt(0) lgkmcnt(0)\n\t"
    :
    : [xwb]"s"(xwb), [wtb]"s"(Wt), [wto]"v"(wtoff), [xo]"v"(xoff0),
      [rda]"v"(rda), [rdb]"v"(rdb), [wra]"v"(wra), [wrb]"v"(wrb),
      [km]"v"(kmulf), [Aa]"v"(Af), [Bb]"v"(Bf),
      [kodd]"v"(kqodd), [khi]"v"(kqhi)
    : "memory", "scc", "s20", "s22", "s23", "s24", "s25",
      "v32","v33","v34","v35","v36","v37","v38","v39",
      "v40","v41","v42","v43","v44","v45","v46","v47",
      "v64","v65","v66","v67","v68","v69","v70","v71",
      "v72","v73","v74","v75","v76","v77","v78","v79",
      "v80","v81","v82","v83","v84","v85","v86","v87",
      "v88","v89","v90","v91","v92","v93","v94","v95",
      "v96","v97","v98","v99","v100","v101","v102","v103",
      "v104","v105","v106","v107","v108","v109","v110","v111",
      "v112","v113","v114","v115","v116","v117","v118","v119",
      "v120","v121","v122","v123","v124","v125","v126","v127",
      "v194","v195","v196","v197","v198","v199",
      "v200","v201","v202","v203","v204","v205","v206","v207",
      "v208","v209","v210","v211","v212","v213","v214","v215",
      "v216","v217","v218","v219",
      "v224","v225","v226","v227");
  __syncthreads();
  // final h (after t=511) is in buffer A as f16: stripe idx (k>>5)*40 + (k&31)
  if (tid < 4) {
    const __half* hf = (const __half*)hlds;
    float acc = b_fc[tid];
#pragma unroll 8
    for (int k = 0; k < HH; ++k)
      acc = fmaf(__half2float(hf[(k >> 5) * 40 + (k & 31)]), W_fc[k * 4 + tid], acc);
    out[b * 4 + tid] = acc;
  }
}

extern "C" void kernel_launch(void* const* d_in, const int* in_sizes, int n_in,
                              void* d_out, int out_size, void* d_ws, size_t ws_size,
                              hipStream_t stream) {
  const float* x_seq   = (const float*)d_in[0];
  const int*   ei      = (const int*)d_in[1];
  const float* w_gat   = (const float*)d_in[2];
  const float* att_src = (const float*)d_in[3];
  const float* att_dst = (const float*)d_in[4];
  const float* b_gat   = (const float*)d_in[5];
  const float* W_ih    = (const float*)d_in[6];
  const float* W_hh    = (const float*)d_in[7];
  const float* b_ih    = (const float*)d_in[8];
  const float* b_hh    = (const float*)d_in[9];
  const float* W_fc    = (const float*)d_in[10];
  const float* b_fc    = (const float*)d_in[11];

  float* ws = (float*)d_ws;
  float* Wt    = ws;                            // 65536 f16 used (region reserved as 65536 f32)
  float* xw    = Wt + 65536;                    // (16384+8)*512 f (pad rows: 4-deep prefetch)
  float* W_eff = xw + (size_t)(NPOS + 8) * G4;  // 32*512
  float* biasp = W_eff + NN * G4;               // 32*512

  prep_kernel<<<NN, G4, 0, stream>>>(w_gat, b_gat, W_ih, W_hh, W_eff, biasp, Wt);
  fused_kernel<<<BB, G4, 0, stream>>>(x_seq, ei, w_gat, att_src, att_dst,
                                      b_ih, b_hh, W_eff, biasp, Wt, W_fc, b_fc,
                                      xw, (float*)d_out);
}

// Round 10
// 426.068 us; speedup vs baseline: 1.1929x; 1.1929x over previous
//
#include <hip/hip_runtime.h>
#include <hip/hip_fp16.h>

#define NN 32      // nodes
#define FF 64      // GAT out features
#define HH 128     // LSTM hidden
#define G4 512     // 4*H
#define BB 32      // batch
#define TT 512     // time steps
#define ET 128     // 96 edges + 32 self loops
#define NPOS (BB*TT)

__device__ __forceinline__ float frcp(float x) { return __builtin_amdgcn_rcpf(x); }

// ---------------- prep: fold GAT linear into LSTM input weights + Wt transpose ----------------
// R20 weight layout (f16): thread tid = r*4+kq. Wt16[tid*128 + P*8 + g*2 + e] =
//   f16(W_hh[(kq*32 + 2P + e)][g*128 + r]),  P=0..15 k-pair, g gate, e parity.
// Also zeroes the producer-consumer flags (runs as the prior dispatch each replay).
__global__ __launch_bounds__(512) void prep_kernel(const float* __restrict__ w_gat,
                                                   const float* __restrict__ b_gat,
                                                   const float* __restrict__ W_ih,
                                                   const float* __restrict__ W_hh,
                                                   float* __restrict__ W_eff,
                                                   float* __restrict__ biasp,
                                                   float* __restrict__ Wt,
                                                   unsigned* __restrict__ flags) {
  int j = threadIdx.x;
  int n = blockIdx.x;
  if (j == 0) flags[n] = 0u;   // 32 flags, zeroed before mega kernel runs
  float accw = 0.f, accb = 0.f;
#pragma unroll 8
  for (int f = 0; f < FF; ++f) {
    float wv = W_ih[(n * FF + f) * G4 + j];
    accw = fmaf(w_gat[f], wv, accw);
    accb = fmaf(b_gat[f], wv, accb);
  }
  W_eff[n * G4 + j] = accw;
  biasp[n * G4 + j] = accb;
  __half* Wt16 = (__half*)Wt;
  int g0 = (n * G4 + j) * 4;
#pragma unroll
  for (int q = 0; q < 4; ++q) {
    int E = g0 + q;
    int tl = E >> 7, idx = E & 127;
    int r = tl >> 2, kq = tl & 3;
    int P = idx >> 3;            // k-pair 0..15
    int g = (idx >> 1) & 3;      // gate
    int e = idx & 1;             // parity within pair
    int k = kq * 32 + 2 * P + e;
    Wt16[E] = __float2half(W_hh[k * G4 + g * 128 + r]);
  }
}

// ---------------- mega: producer blocks (gatxw, full parallelism) + consumer blocks (scan) ----
// R21 decomposition: gap = ~77us fixed harness overhead + ~3 prep + ~26us gatxw dispatch.
// R22 recovers the 26us: one 288-block dispatch. Blocks 0-31 run the verified R20 scan
// (spin on flags first); blocks 32-287 are gatxw producers (8 per batch x 64 positions,
// 256-way parallelism on the 224 CUs the scan doesn't use). Handshake: producer
// syncthreads -> threadfence (wbL2 release) -> atomicAdd flag; consumer spins
// (device-scope atomic read), then threadfence (L2 inv acquire; also clears stale lines
// from previous graph replay). No deadlock: consumers(32) <= CUs, producers dep-free,
// all 288 blocks co-resident.

#define D2F(HJ, W0, W1, W2, W3) \
  "v_dot2_f32_f16 v216, v" HJ ", v" W0 ", 0\n\t" \
  "v_dot2_f32_f16 v217, v" HJ ", v" W1 ", 0\n\t" \
  "v_dot2_f32_f16 v218, v" HJ ", v" W2 ", 0\n\t" \
  "v_dot2_f32_f16 v219, v" HJ ", v" W3 ", 0\n\t"

#define D2A(HJ, W0, W1, W2, W3) \
  "v_dot2_f32_f16 v216, v" HJ ", v" W0 ", v216\n\t" \
  "v_dot2_f32_f16 v217, v" HJ ", v" W1 ", v217\n\t" \
  "v_dot2_f32_f16 v218, v" HJ ", v" W2 ", v218\n\t" \
  "v_dot2_f32_f16 v219, v" HJ ", v" W3 ", v219\n\t"

#define PHASE(XSLOT, RD, WR) \
  "ds_read_b128 v[32:35], " RD "\n\t" \
  "ds_read_b128 v[36:39], " RD " offset:16\n\t" \
  "ds_read_b128 v[40:43], " RD " offset:32\n\t" \
  "ds_read_b128 v[44:47], " RD " offset:48\n\t" \
  "s_waitcnt lgkmcnt(3)\n\t" \
  D2F("32", "64", "65", "66", "67") \
  D2A("33", "68", "69", "70", "71") \
  D2A("34", "72", "73", "74", "75") \
  D2A("35", "76", "77", "78", "79") \
  "s_waitcnt lgkmcnt(2)\n\t" \
  D2A("36", "80", "81", "82", "83") \
  D2A("37", "84", "85", "86", "87") \
  D2A("38", "88", "89", "90", "91") \
  D2A("39", "92", "93", "94", "95") \
  "s_waitcnt lgkmcnt(1)\n\t" \
  D2A("40", "96", "97", "98", "99") \
  D2A("41", "100", "101", "102", "103") \
  D2A("42", "104", "105", "106", "107") \
  D2A("43", "108", "109", "110", "111") \
  "s_waitcnt lgkmcnt(0)\n\t" \
  D2A("44", "112", "113", "114", "115") \
  D2A("45", "116", "117", "118", "119") \
  D2A("46", "120", "121", "122", "123") \
  D2A("47", "124", "125", "126", "127") \
  "v_add_f32_dpp v216, v216, v216 quad_perm:[1,0,3,2] row_mask:0xf bank_mask:0xf\n\t" \
  "v_add_f32_dpp v217, v217, v217 quad_perm:[1,0,3,2] row_mask:0xf bank_mask:0xf\n\t" \
  "v_add_f32_dpp v218, v218, v218 quad_perm:[1,0,3,2] row_mask:0xf bank_mask:0xf\n\t" \
  "v_add_f32_dpp v219, v219, v219 quad_perm:[1,0,3,2] row_mask:0xf bank_mask:0xf\n\t" \
  "v_add_f32_dpp v216, v216, v216 quad_perm:[2,3,0,1] row_mask:0xf bank_mask:0xf\n\t" \
  "v_add_f32_dpp v217, v217, v217 quad_perm:[2,3,0,1] row_mask:0xf bank_mask:0xf\n\t" \
  "v_add_f32_dpp v218, v218, v218 quad_perm:[2,3,0,1] row_mask:0xf bank_mask:0xf\n\t" \
  "v_add_f32_dpp v219, v219, v219 quad_perm:[2,3,0,1] row_mask:0xf bank_mask:0xf\n\t" \
  "v_cndmask_b32 v208, v216, v217, s[22:23]\n\t" \
  "v_cndmask_b32 v209, v218, v219, s[22:23]\n\t" \
  "v_cndmask_b32 v208, v208, v209, s[24:25]\n\t" \
  "s_waitcnt vmcnt(3)\n\t" \
  "v_mov_b32 v215, " XSLOT "\n\t" \
  "global_load_dword " XSLOT ", v194, %[xwb]\n\t" \
  "v_add_u32 v194, 0x800, v194\n\t" \
  "v_add_f32 v208, v208, v215\n\t" \
  "v_mul_f32 v209, v200, v208\n\t" \
  "v_exp_f32 v209, v209\n\t" \
  "s_nop 0\n\t" \
  "v_add_f32 v209, 1.0, v209\n\t" \
  "v_rcp_f32 v209, v209\n\t" \
  "s_nop 0\n\t" \
  "v_fma_f32 v210, v201, v209, v202\n\t" \
  "s_nop 1\n\t" \
  "v_add_f32_dpp v211, v210, v203 quad_perm:[0,0,0,0] row_mask:0xf bank_mask:0xf\n\t" \
  "v_add_f32_dpp v212, v210, v203 quad_perm:[1,1,1,1] row_mask:0xf bank_mask:0xf\n\t" \
  "v_add_f32_dpp v213, v210, v203 quad_perm:[2,2,2,2] row_mask:0xf bank_mask:0xf\n\t" \
  "v_add_f32_dpp v214, v210, v203 quad_perm:[3,3,3,3] row_mask:0xf bank_mask:0xf\n\t" \
  "v_mul_f32 v211, v211, v213\n\t" \
  "v_fma_f32 v199, v212, v199, v211\n\t" \
  "v_mul_f32 v209, 0x4038aa3b, v199\n\t" \
  "v_exp_f32 v209, v209\n\t" \
  "s_nop 0\n\t" \
  "v_add_f32 v209, 1.0, v209\n\t" \
  "v_rcp_f32 v209, v209\n\t" \
  "s_nop 0\n\t" \
  "v_fma_f32 v209, -2.0, v209, 1.0\n\t" \
  "v_mul_f32 v209, v214, v209\n\t" \
  "v_cvt_f16_f32 v209, v209\n\t" \
  "ds_write_b16 " WR ", v209\n\t" \
  "s_waitcnt lgkmcnt(0)\n\t" \
  "s_barrier\n\t"

__global__ __launch_bounds__(512, 2) void mega_kernel(const float* __restrict__ x_seq,
                                                      const int* __restrict__ ei,
                                                      const float* __restrict__ w_gat,
                                                      const float* __restrict__ att_src,
                                                      const float* __restrict__ att_dst,
                                                      const float* __restrict__ b_ih,
                                                      const float* __restrict__ b_hh,
                                                      const float* __restrict__ W_eff,
                                                      const float* __restrict__ biasp,
                                                      const float* __restrict__ Wt,
                                                      const float* __restrict__ W_fc,
                                                      const float* __restrict__ b_fc,
                                                      float* __restrict__ xw,
                                                      unsigned* __restrict__ flags,
                                                      float* __restrict__ out) {
  __shared__ int srt[ET];
  __shared__ int offs[NN + 1];
  __shared__ int cnt[NN];
  __shared__ float xs[64 * NN];   // 2048: producer round buffer
  __shared__ float sl[64 * NN];   // 2048
  __shared__ float scal_sh[2];
  __shared__ __align__(16) float hlds[160];  // consumer f16 h: hA [0,320)B, hB [320,640)B
  int tid = threadIdx.x;
  int blk = blockIdx.x;

  if (blk >= BB) {
    // ================= producer: gatxw for 64 positions =================
    int pb = blk - BB;             // 0..255
    int bb = pb >> 3;              // batch
    int posbase = pb * 64;         // global position base
    float wcol[NN];
#pragma unroll
    for (int nn = 0; nn < NN; ++nn) wcol[nn] = W_eff[nn * G4 + tid];
    float bcol = b_ih[tid] + b_hh[tid];
#pragma unroll 8
    for (int nn = 0; nn < NN; ++nn) bcol += biasp[nn * G4 + tid];
    if (tid < NN) cnt[tid] = 0;
    __syncthreads();
    int es = 0, ed = 0, tk = 0;
    if (tid < ET) {
      if (tid < 96) { es = ei[tid]; ed = ei[96 + tid]; }
      else { es = tid - 96; ed = tid - 96; }
      tk = atomicAdd(&cnt[ed], 1);
    }
    __syncthreads();
    if (tid == 0) {
      offs[0] = 0;
      for (int n = 0; n < NN; ++n) offs[n + 1] = offs[n] + cnt[n];
    }
    if (tid == 1) {
      float cs = 0.f, cd = 0.f;
      for (int f = 0; f < FF; ++f) {
        cs = fmaf(w_gat[f], att_src[f], cs);
        cd = fmaf(w_gat[f], att_dst[f], cd);
      }
      scal_sh[0] = cs;
      scal_sh[1] = cd;
    }
    __syncthreads();
    if (tid < ET) srt[offs[ed] + tk] = es;
#pragma unroll
    for (int c = 0; c < 4; ++c)
      xs[c * 512 + tid] = x_seq[(size_t)posbase * NN + c * 512 + tid];  // coalesced
    __syncthreads();
    float cs = scal_sh[0], cd = scal_sh[1];
    int n = tid & 31;
    int e0 = offs[n], e1 = offs[n + 1];
#pragma unroll
    for (int rr = 0; rr < 4; ++rr) {               // softmax: 4 rounds x 16 positions
      int p = rr * 16 + (tid >> 5);
      int base = p * 32;
      float xn = xs[base + n];
      float cdxn = cd * xn;
      float m = -3.0e38f;
      for (int e = e0; e < e1; ++e) {
        float ev = fmaf(cs, xs[base + srt[e]], cdxn);
        ev = ev > 0.f ? ev : 0.2f * ev;             // LeakyReLU(0.2)
        m = fmaxf(m, ev);
      }
      float z = 0.f, sa = 0.f;
      for (int e = e0; e < e1; ++e) {
        float xsv = xs[base + srt[e]];
        float ev = fmaf(cs, xsv, cdxn);
        ev = ev > 0.f ? ev : 0.2f * ev;
        float ex = __expf(ev - m);
        z += ex;
        sa = fmaf(ex, xsv, sa);
      }
      sl[base + n] = sa * frcp(z);
    }
    __syncthreads();
#pragma unroll 4
    for (int pp = 0; pp < 64; ++pp) {              // GEMV: column tid over 32 nodes
      const float4* sp = (const float4*)&sl[pp * 32];
      float a0 = bcol;
#pragma unroll
      for (int q = 0; q < 8; ++q) {
        float4 sv = sp[q];
        a0 = fmaf(sv.x, wcol[4 * q], a0);
        a0 = fmaf(sv.y, wcol[4 * q + 1], a0);
        a0 = fmaf(sv.z, wcol[4 * q + 2], a0);
        a0 = fmaf(sv.w, wcol[4 * q + 3], a0);
      }
      xw[(size_t)(posbase + pp) * G4 + tid] = a0;
    }
    __syncthreads();
    __threadfence();                               // release: push xw to coherent point
    if (tid == 0) atomicAdd(&flags[bb], 1u);
    return;
  }

  // ================= consumer: R20 LSTM scan for batch blk =================
  int b = blk;
  if (tid < 160) hlds[tid] = 0.f;                  // f16 zeros
  if (tid == 0) {
    while (atomicAdd(&flags[b], 0u) < 8u) { __builtin_amdgcn_s_sleep(8); }
  }
  __syncthreads();
  __threadfence();                                 // acquire: invalidate stale L2 lines
  int r = tid >> 2, kq = tid & 3;
  const float* xwb = xw + (size_t)b * TT * G4;
  unsigned xoff0 = (unsigned)((kq * 128 + r) * 4); // t=0 (xw is f32)
  unsigned wtoff = (unsigned)(tid * 256);          // 128 f16 = 256 B per thread
  unsigned lbase = (unsigned)(uintptr_t)&hlds[0];  // LDS aperture is 4GB-aligned
  unsigned rda = lbase + (unsigned)(kq * 80);      // quarter kq: 32 f16 = 64B (stripe 40 f16)
  unsigned rdb = rda + 320;
  unsigned wra = lbase + (unsigned)(((r >> 5) * 40 + (r & 31)) * 2);  // f16 element
  unsigned wrb = wra + 320;
  float kmulf = (kq == 2) ? __uint_as_float(0x4038aa3bu)   //  2*log2e
                          : __uint_as_float(0xbfb8aa3bu);  // -log2e
  float Af = (kq == 2) ? -2.f : 1.f;
  float Bf = (kq == 2) ? 1.f : 0.f;
  unsigned kqodd = kq & 1, kqhi = kq >> 1;
  __syncthreads();
  asm volatile(
    "v_mov_b32 v194, %[xo]\n\t"
    "v_mov_b32 v195, %[rda]\n\t"
    "v_mov_b32 v196, %[rdb]\n\t"
    "v_mov_b32 v197, %[wra]\n\t"
    "v_mov_b32 v198, %[wrb]\n\t"
    "v_mov_b32 v199, 0\n\t"          // c
    "v_mov_b32 v200, %[km]\n\t"      // kmul
    "v_mov_b32 v201, %[Aa]\n\t"      // A
    "v_mov_b32 v202, %[Bb]\n\t"      // B
    "v_mov_b32 v203, 0\n\t"          // zero (DPP-gather src1)
    "v_cmp_eq_u32 s[22:23], 1, %[kodd]\n\t"
    "v_cmp_eq_u32 s[24:25], 1, %[khi]\n\t"
    // x prefetch ring: t=0..3 -> v224..v227
    "global_load_dword v224, v194, %[xwb]\n\t"
    "v_add_u32 v194, 0x800, v194\n\t"
    "global_load_dword v225, v194, %[xwb]\n\t"
    "v_add_u32 v194, 0x800, v194\n\t"
    "global_load_dword v226, v194, %[xwb]\n\t"
    "v_add_u32 v194, 0x800, v194\n\t"
    "global_load_dword v227, v194, %[xwb]\n\t"
    "v_add_u32 v194, 0x800, v194\n\t"
    // 128 f16 weights -> v64..v127 (16 x dwordx4)
    "global_load_dwordx4 v[64:67], %[wto], %[wtb] offset:0\n\t"
    "global_load_dwordx4 v[68:71], %[wto], %[wtb] offset:16\n\t"
    "global_load_dwordx4 v[72:75], %[wto], %[wtb] offset:32\n\t"
    "global_load_dwordx4 v[76:79], %[wto], %[wtb] offset:48\n\t"
    "global_load_dwordx4 v[80:83], %[wto], %[wtb] offset:64\n\t"
    "global_load_dwordx4 v[84:87], %[wto], %[wtb] offset:80\n\t"
    "global_load_dwordx4 v[88:91], %[wto], %[wtb] offset:96\n\t"
    "global_load_dwordx4 v[92:95], %[wto], %[wtb] offset:112\n\t"
    "global_load_dwordx4 v[96:99], %[wto], %[wtb] offset:128\n\t"
    "global_load_dwordx4 v[100:103], %[wto], %[wtb] offset:144\n\t"
    "global_load_dwordx4 v[104:107], %[wto], %[wtb] offset:160\n\t"
    "global_load_dwordx4 v[108:111], %[wto], %[wtb] offset:176\n\t"
    "global_load_dwordx4 v[112:115], %[wto], %[wtb] offset:192\n\t"
    "global_load_dwordx4 v[116:119], %[wto], %[wtb] offset:208\n\t"
    "global_load_dwordx4 v[120:123], %[wto], %[wtb] offset:224\n\t"
    "global_load_dwordx4 v[124:127], %[wto], %[wtb] offset:240\n\t"
    "s_waitcnt vmcnt(0)\n\t"
    "s_movk_i32 s20, 0x80\n\t"    // 128 iterations x 4 phases = 512 steps
    "L_lstm_%=:\n\t"
    PHASE("v224", "v195", "v198")   // t%4==0: read A, write B
    PHASE("v225", "v196", "v197")   // t%4==1: read B, write A
    PHASE("v226", "v195", "v198")   // t%4==2: read A, write B
    PHASE("v227", "v196", "v197")   // t%4==3: read B, write A
    "s_sub_u32 s20, s20, 1\n\t"
    "s_cmp_lg_u32 s20, 0\n\t"
    "s_cbranch_scc1 L_lstm_%=\n\t"
    "s_waitcnt vmcnt(0) lgkmcnt(0)\n\t"
    :
    : [xwb]"s"(xwb), [wtb]"s"(Wt), [wto]"v"(wtoff), [xo]"v"(xoff0),
      [rda]"v"(rda), [rdb]"v"(rdb), [wra]"v"(wra), [wrb]"v"(wrb),
      [km]"v"(kmulf), [Aa]"v"(Af), [Bb]"v"(Bf),
      [kodd]"v"(kqodd), [khi]"v"(kqhi)
    : "memory", "scc", "s20", "s22", "s23", "s24", "s25",
      "v32","v33","v34","v35","v36","v37","v38","v39",
      "v40","v41","v42","v43","v44","v45","v46","v47",
      "v64","v65","v66","v67","v68","v69","v70","v71",
      "v72","v73","v74","v75","v76","v77","v78","v79",
      "v80","v81","v82","v83","v84","v85","v86","v87",
      "v88","v89","v90","v91","v92","v93","v94","v95",
      "v96","v97","v98","v99","v100","v101","v102","v103",
      "v104","v105","v106","v107","v108","v109","v110","v111",
      "v112","v113","v114","v115","v116","v117","v118","v119",
      "v120","v121","v122","v123","v124","v125","v126","v127",
      "v194","v195","v196","v197","v198","v199",
      "v200","v201","v202","v203","v204","v205","v206","v207",
      "v208","v209","v210","v211","v212","v213","v214","v215",
      "v216","v217","v218","v219",
      "v224","v225","v226","v227");
  __syncthreads();
  // final h (after t=511) is in buffer A as f16: stripe idx (k>>5)*40 + (k&31)
  if (tid < 4) {
    const __half* hf = (const __half*)hlds;
    float acc = b_fc[tid];
#pragma unroll 8
    for (int k = 0; k < HH; ++k)
      acc = fmaf(__half2float(hf[(k >> 5) * 40 + (k & 31)]), W_fc[k * 4 + tid], acc);
    out[b * 4 + tid] = acc;
  }
}

extern "C" void kernel_launch(void* const* d_in, const int* in_sizes, int n_in,
                              void* d_out, int out_size, void* d_ws, size_t ws_size,
                              hipStream_t stream) {
  const float* x_seq   = (const float*)d_in[0];
  const int*   ei      = (const int*)d_in[1];
  const float* w_gat   = (const float*)d_in[2];
  const float* att_src = (const float*)d_in[3];
  const float* att_dst = (const float*)d_in[4];
  const float* b_gat   = (const float*)d_in[5];
  const float* W_ih    = (const float*)d_in[6];
  const float* W_hh    = (const float*)d_in[7];
  const float* b_ih    = (const float*)d_in[8];
  const float* b_hh    = (const float*)d_in[9];
  const float* W_fc    = (const float*)d_in[10];
  const float* b_fc    = (const float*)d_in[11];

  float* ws = (float*)d_ws;
  float* Wt    = ws;                            // 65536 f16 used (region reserved as 65536 f32)
  float* xw    = Wt + 65536;                    // (16384+8)*512 f (pad rows: 4-deep prefetch)
  float* W_eff = xw + (size_t)(NPOS + 8) * G4;  // 32*512
  float* biasp = W_eff + NN * G4;               // 32*512
  unsigned* flags = (unsigned*)(biasp + NN * G4);  // 32 flags

  prep_kernel<<<NN, G4, 0, stream>>>(w_gat, b_gat, W_ih, W_hh, W_eff, biasp, Wt, flags);
  mega_kernel<<<BB + 256, G4, 0, stream>>>(x_seq, ei, w_gat, att_src, att_dst,
                                           b_ih, b_hh, W_eff, biasp, Wt, W_fc, b_fc,
                                           xw, flags, (float*)d_out);
}

// Round 11
// 419.967 us; speedup vs baseline: 1.2102x; 1.0145x over previous
//
#include <hip/hip_runtime.h>
#include <hip/hip_fp16.h>

#define NN 32      // nodes
#define FF 64      // GAT out features
#define HH 128     // LSTM hidden
#define G4 512     // 4*H
#define BB 32      // batch
#define TT 512     // time steps
#define ET 128     // 96 edges + 32 self loops
#define NPOS (BB*TT)

__device__ __forceinline__ float frcp(float x) { return __builtin_amdgcn_rcpf(x); }

// ---------------- prep: fold GAT linear into LSTM input weights + Wt transpose ----------------
// R20 weight layout (f16): thread tid = r*4+kq. Wt16[tid*128 + P*8 + g*2 + e] =
//   f16(W_hh[(kq*32 + 2P + e)][g*128 + r]),  P=0..15 k-pair, g gate, e parity.
// Also zeroes the producer-consumer flags (runs as the prior dispatch each replay).
__global__ __launch_bounds__(512) void prep_kernel(const float* __restrict__ w_gat,
                                                   const float* __restrict__ b_gat,
                                                   const float* __restrict__ W_ih,
                                                   const float* __restrict__ W_hh,
                                                   float* __restrict__ W_eff,
                                                   float* __restrict__ biasp,
                                                   float* __restrict__ Wt,
                                                   unsigned* __restrict__ flags) {
  int j = threadIdx.x;
  int n = blockIdx.x;
  if (j == 0) flags[n] = 0u;   // 32 flags, zeroed before mega kernel runs
  float accw = 0.f, accb = 0.f;
#pragma unroll 8
  for (int f = 0; f < FF; ++f) {
    float wv = W_ih[(n * FF + f) * G4 + j];
    accw = fmaf(w_gat[f], wv, accw);
    accb = fmaf(b_gat[f], wv, accb);
  }
  W_eff[n * G4 + j] = accw;
  biasp[n * G4 + j] = accb;
  __half* Wt16 = (__half*)Wt;
  int g0 = (n * G4 + j) * 4;
#pragma unroll
  for (int q = 0; q < 4; ++q) {
    int E = g0 + q;
    int tl = E >> 7, idx = E & 127;
    int r = tl >> 2, kq = tl & 3;
    int P = idx >> 3;            // k-pair 0..15
    int g = (idx >> 1) & 3;      // gate
    int e = idx & 1;             // parity within pair
    int k = kq * 32 + 2 * P + e;
    Wt16[E] = __float2half(W_hh[k * G4 + g * 128 + r]);
  }
}

// ---------------- mega: producers + consumers, INTERLEAVED placement ----------------
// R22 post-mortem: launch_bounds(512,2) packs consecutive blocks 2-per-CU; consumers
// (blocks 0-31) paired on 16 CUs -> two scans shared each CU's SIMDs: step ~1600cy,
// 345us = 1.385 x 249 (VALUBusy ROSE 8.4->9.6: doubled per-CU issue, not slow producers).
// R23: consumer iff blk%9==0 (spacing 9 > 2 defeats packed pairing; distinct mod 256
// for round-robin). Producer pb = blk - blk/9 - 1 (bijective 0..255). All else identical.

#define D2F(HJ, W0, W1, W2, W3) \
  "v_dot2_f32_f16 v216, v" HJ ", v" W0 ", 0\n\t" \
  "v_dot2_f32_f16 v217, v" HJ ", v" W1 ", 0\n\t" \
  "v_dot2_f32_f16 v218, v" HJ ", v" W2 ", 0\n\t" \
  "v_dot2_f32_f16 v219, v" HJ ", v" W3 ", 0\n\t"

#define D2A(HJ, W0, W1, W2, W3) \
  "v_dot2_f32_f16 v216, v" HJ ", v" W0 ", v216\n\t" \
  "v_dot2_f32_f16 v217, v" HJ ", v" W1 ", v217\n\t" \
  "v_dot2_f32_f16 v218, v" HJ ", v" W2 ", v218\n\t" \
  "v_dot2_f32_f16 v219, v" HJ ", v" W3 ", v219\n\t"

#define PHASE(XSLOT, RD, WR) \
  "ds_read_b128 v[32:35], " RD "\n\t" \
  "ds_read_b128 v[36:39], " RD " offset:16\n\t" \
  "ds_read_b128 v[40:43], " RD " offset:32\n\t" \
  "ds_read_b128 v[44:47], " RD " offset:48\n\t" \
  "s_waitcnt lgkmcnt(3)\n\t" \
  D2F("32", "64", "65", "66", "67") \
  D2A("33", "68", "69", "70", "71") \
  D2A("34", "72", "73", "74", "75") \
  D2A("35", "76", "77", "78", "79") \
  "s_waitcnt lgkmcnt(2)\n\t" \
  D2A("36", "80", "81", "82", "83") \
  D2A("37", "84", "85", "86", "87") \
  D2A("38", "88", "89", "90", "91") \
  D2A("39", "92", "93", "94", "95") \
  "s_waitcnt lgkmcnt(1)\n\t" \
  D2A("40", "96", "97", "98", "99") \
  D2A("41", "100", "101", "102", "103") \
  D2A("42", "104", "105", "106", "107") \
  D2A("43", "108", "109", "110", "111") \
  "s_waitcnt lgkmcnt(0)\n\t" \
  D2A("44", "112", "113", "114", "115") \
  D2A("45", "116", "117", "118", "119") \
  D2A("46", "120", "121", "122", "123") \
  D2A("47", "124", "125", "126", "127") \
  "v_add_f32_dpp v216, v216, v216 quad_perm:[1,0,3,2] row_mask:0xf bank_mask:0xf\n\t" \
  "v_add_f32_dpp v217, v217, v217 quad_perm:[1,0,3,2] row_mask:0xf bank_mask:0xf\n\t" \
  "v_add_f32_dpp v218, v218, v218 quad_perm:[1,0,3,2] row_mask:0xf bank_mask:0xf\n\t" \
  "v_add_f32_dpp v219, v219, v219 quad_perm:[1,0,3,2] row_mask:0xf bank_mask:0xf\n\t" \
  "v_add_f32_dpp v216, v216, v216 quad_perm:[2,3,0,1] row_mask:0xf bank_mask:0xf\n\t" \
  "v_add_f32_dpp v217, v217, v217 quad_perm:[2,3,0,1] row_mask:0xf bank_mask:0xf\n\t" \
  "v_add_f32_dpp v218, v218, v218 quad_perm:[2,3,0,1] row_mask:0xf bank_mask:0xf\n\t" \
  "v_add_f32_dpp v219, v219, v219 quad_perm:[2,3,0,1] row_mask:0xf bank_mask:0xf\n\t" \
  "v_cndmask_b32 v208, v216, v217, s[22:23]\n\t" \
  "v_cndmask_b32 v209, v218, v219, s[22:23]\n\t" \
  "v_cndmask_b32 v208, v208, v209, s[24:25]\n\t" \
  "s_waitcnt vmcnt(3)\n\t" \
  "v_mov_b32 v215, " XSLOT "\n\t" \
  "global_load_dword " XSLOT ", v194, %[xwb]\n\t" \
  "v_add_u32 v194, 0x800, v194\n\t" \
  "v_add_f32 v208, v208, v215\n\t" \
  "v_mul_f32 v209, v200, v208\n\t" \
  "v_exp_f32 v209, v209\n\t" \
  "s_nop 0\n\t" \
  "v_add_f32 v209, 1.0, v209\n\t" \
  "v_rcp_f32 v209, v209\n\t" \
  "s_nop 0\n\t" \
  "v_fma_f32 v210, v201, v209, v202\n\t" \
  "s_nop 1\n\t" \
  "v_add_f32_dpp v211, v210, v203 quad_perm:[0,0,0,0] row_mask:0xf bank_mask:0xf\n\t" \
  "v_add_f32_dpp v212, v210, v203 quad_perm:[1,1,1,1] row_mask:0xf bank_mask:0xf\n\t" \
  "v_add_f32_dpp v213, v210, v203 quad_perm:[2,2,2,2] row_mask:0xf bank_mask:0xf\n\t" \
  "v_add_f32_dpp v214, v210, v203 quad_perm:[3,3,3,3] row_mask:0xf bank_mask:0xf\n\t" \
  "v_mul_f32 v211, v211, v213\n\t" \
  "v_fma_f32 v199, v212, v199, v211\n\t" \
  "v_mul_f32 v209, 0x4038aa3b, v199\n\t" \
  "v_exp_f32 v209, v209\n\t" \
  "s_nop 0\n\t" \
  "v_add_f32 v209, 1.0, v209\n\t" \
  "v_rcp_f32 v209, v209\n\t" \
  "s_nop 0\n\t" \
  "v_fma_f32 v209, -2.0, v209, 1.0\n\t" \
  "v_mul_f32 v209, v214, v209\n\t" \
  "v_cvt_f16_f32 v209, v209\n\t" \
  "ds_write_b16 " WR ", v209\n\t" \
  "s_waitcnt lgkmcnt(0)\n\t" \
  "s_barrier\n\t"

__global__ __launch_bounds__(512, 2) void mega_kernel(const float* __restrict__ x_seq,
                                                      const int* __restrict__ ei,
                                                      const float* __restrict__ w_gat,
                                                      const float* __restrict__ att_src,
                                                      const float* __restrict__ att_dst,
                                                      const float* __restrict__ b_ih,
                                                      const float* __restrict__ b_hh,
                                                      const float* __restrict__ W_eff,
                                                      const float* __restrict__ biasp,
                                                      const float* __restrict__ Wt,
                                                      const float* __restrict__ W_fc,
                                                      const float* __restrict__ b_fc,
                                                      float* __restrict__ xw,
                                                      unsigned* __restrict__ flags,
                                                      float* __restrict__ out) {
  __shared__ int srt[ET];
  __shared__ int offs[NN + 1];
  __shared__ int cnt[NN];
  __shared__ float xs[64 * NN];   // 2048: producer round buffer
  __shared__ float sl[64 * NN];   // 2048
  __shared__ float scal_sh[2];
  __shared__ __align__(16) float hlds[160];  // consumer f16 h: hA [0,320)B, hB [320,640)B
  int tid = threadIdx.x;
  int blk = blockIdx.x;
  bool is_consumer = (blk % 9) == 0;

  if (!is_consumer) {
    // ================= producer: gatxw for 64 positions =================
    int pb = blk - blk / 9 - 1;    // bijective onto 0..255
    int bb = pb >> 3;              // batch
    int posbase = pb * 64;         // global position base
    float wcol[NN];
#pragma unroll
    for (int nn = 0; nn < NN; ++nn) wcol[nn] = W_eff[nn * G4 + tid];
    float bcol = b_ih[tid] + b_hh[tid];
#pragma unroll 8
    for (int nn = 0; nn < NN; ++nn) bcol += biasp[nn * G4 + tid];
    if (tid < NN) cnt[tid] = 0;
    __syncthreads();
    int es = 0, ed = 0, tk = 0;
    if (tid < ET) {
      if (tid < 96) { es = ei[tid]; ed = ei[96 + tid]; }
      else { es = tid - 96; ed = tid - 96; }
      tk = atomicAdd(&cnt[ed], 1);
    }
    __syncthreads();
    if (tid == 0) {
      offs[0] = 0;
      for (int n = 0; n < NN; ++n) offs[n + 1] = offs[n] + cnt[n];
    }
    if (tid == 1) {
      float cs = 0.f, cd = 0.f;
      for (int f = 0; f < FF; ++f) {
        cs = fmaf(w_gat[f], att_src[f], cs);
        cd = fmaf(w_gat[f], att_dst[f], cd);
      }
      scal_sh[0] = cs;
      scal_sh[1] = cd;
    }
    __syncthreads();
    if (tid < ET) srt[offs[ed] + tk] = es;
#pragma unroll
    for (int c = 0; c < 4; ++c)
      xs[c * 512 + tid] = x_seq[(size_t)posbase * NN + c * 512 + tid];  // coalesced
    __syncthreads();
    float cs = scal_sh[0], cd = scal_sh[1];
    int n = tid & 31;
    int e0 = offs[n], e1 = offs[n + 1];
#pragma unroll
    for (int rr = 0; rr < 4; ++rr) {               // softmax: 4 rounds x 16 positions
      int p = rr * 16 + (tid >> 5);
      int base = p * 32;
      float xn = xs[base + n];
      float cdxn = cd * xn;
      float m = -3.0e38f;
      for (int e = e0; e < e1; ++e) {
        float ev = fmaf(cs, xs[base + srt[e]], cdxn);
        ev = ev > 0.f ? ev : 0.2f * ev;             // LeakyReLU(0.2)
        m = fmaxf(m, ev);
      }
      float z = 0.f, sa = 0.f;
      for (int e = e0; e < e1; ++e) {
        float xsv = xs[base + srt[e]];
        float ev = fmaf(cs, xsv, cdxn);
        ev = ev > 0.f ? ev : 0.2f * ev;
        float ex = __expf(ev - m);
        z += ex;
        sa = fmaf(ex, xsv, sa);
      }
      sl[base + n] = sa * frcp(z);
    }
    __syncthreads();
#pragma unroll 4
    for (int pp = 0; pp < 64; ++pp) {              // GEMV: column tid over 32 nodes
      const float4* sp = (const float4*)&sl[pp * 32];
      float a0 = bcol;
#pragma unroll
      for (int q = 0; q < 8; ++q) {
        float4 sv = sp[q];
        a0 = fmaf(sv.x, wcol[4 * q], a0);
        a0 = fmaf(sv.y, wcol[4 * q + 1], a0);
        a0 = fmaf(sv.z, wcol[4 * q + 2], a0);
        a0 = fmaf(sv.w, wcol[4 * q + 3], a0);
      }
      xw[(size_t)(posbase + pp) * G4 + tid] = a0;
    }
    __syncthreads();
    __threadfence();                               // release: push xw to coherent point
    if (tid == 0) atomicAdd(&flags[bb], 1u);
    return;
  }

  // ================= consumer: R20 LSTM scan for batch blk/9 =================
  int b = blk / 9;
  if (tid < 160) hlds[tid] = 0.f;                  // f16 zeros
  if (tid == 0) {
    while (atomicAdd(&flags[b], 0u) < 8u) { __builtin_amdgcn_s_sleep(8); }
  }
  __syncthreads();
  __threadfence();                                 // acquire: invalidate stale L2 lines
  int r = tid >> 2, kq = tid & 3;
  const float* xwb = xw + (size_t)b * TT * G4;
  unsigned xoff0 = (unsigned)((kq * 128 + r) * 4); // t=0 (xw is f32)
  unsigned wtoff = (unsigned)(tid * 256);          // 128 f16 = 256 B per thread
  unsigned lbase = (unsigned)(uintptr_t)&hlds[0];  // LDS aperture is 4GB-aligned
  unsigned rda = lbase + (unsigned)(kq * 80);      // quarter kq: 32 f16 = 64B (stripe 40 f16)
  unsigned rdb = rda + 320;
  unsigned wra = lbase + (unsigned)(((r >> 5) * 40 + (r & 31)) * 2);  // f16 element
  unsigned wrb = wra + 320;
  float kmulf = (kq == 2) ? __uint_as_float(0x4038aa3bu)   //  2*log2e
                          : __uint_as_float(0xbfb8aa3bu);  // -log2e
  float Af = (kq == 2) ? -2.f : 1.f;
  float Bf = (kq == 2) ? 1.f : 0.f;
  unsigned kqodd = kq & 1, kqhi = kq >> 1;
  __syncthreads();
  asm volatile(
    "v_mov_b32 v194, %[xo]\n\t"
    "v_mov_b32 v195, %[rda]\n\t"
    "v_mov_b32 v196, %[rdb]\n\t"
    "v_mov_b32 v197, %[wra]\n\t"
    "v_mov_b32 v198, %[wrb]\n\t"
    "v_mov_b32 v199, 0\n\t"          // c
    "v_mov_b32 v200, %[km]\n\t"      // kmul
    "v_mov_b32 v201, %[Aa]\n\t"      // A
    "v_mov_b32 v202, %[Bb]\n\t"      // B
    "v_mov_b32 v203, 0\n\t"          // zero (DPP-gather src1)
    "v_cmp_eq_u32 s[22:23], 1, %[kodd]\n\t"
    "v_cmp_eq_u32 s[24:25], 1, %[khi]\n\t"
    // x prefetch ring: t=0..3 -> v224..v227
    "global_load_dword v224, v194, %[xwb]\n\t"
    "v_add_u32 v194, 0x800, v194\n\t"
    "global_load_dword v225, v194, %[xwb]\n\t"
    "v_add_u32 v194, 0x800, v194\n\t"
    "global_load_dword v226, v194, %[xwb]\n\t"
    "v_add_u32 v194, 0x800, v194\n\t"
    "global_load_dword v227, v194, %[xwb]\n\t"
    "v_add_u32 v194, 0x800, v194\n\t"
    // 128 f16 weights -> v64..v127 (16 x dwordx4)
    "global_load_dwordx4 v[64:67], %[wto], %[wtb] offset:0\n\t"
    "global_load_dwordx4 v[68:71], %[wto], %[wtb] offset:16\n\t"
    "global_load_dwordx4 v[72:75], %[wto], %[wtb] offset:32\n\t"
    "global_load_dwordx4 v[76:79], %[wto], %[wtb] offset:48\n\t"
    "global_load_dwordx4 v[80:83], %[wto], %[wtb] offset:64\n\t"
    "global_load_dwordx4 v[84:87], %[wto], %[wtb] offset:80\n\t"
    "global_load_dwordx4 v[88:91], %[wto], %[wtb] offset:96\n\t"
    "global_load_dwordx4 v[92:95], %[wto], %[wtb] offset:112\n\t"
    "global_load_dwordx4 v[96:99], %[wto], %[wtb] offset:128\n\t"
    "global_load_dwordx4 v[100:103], %[wto], %[wtb] offset:144\n\t"
    "global_load_dwordx4 v[104:107], %[wto], %[wtb] offset:160\n\t"
    "global_load_dwordx4 v[108:111], %[wto], %[wtb] offset:176\n\t"
    "global_load_dwordx4 v[112:115], %[wto], %[wtb] offset:192\n\t"
    "global_load_dwordx4 v[116:119], %[wto], %[wtb] offset:208\n\t"
    "global_load_dwordx4 v[120:123], %[wto], %[wtb] offset:224\n\t"
    "global_load_dwordx4 v[124:127], %[wto], %[wtb] offset:240\n\t"
    "s_waitcnt vmcnt(0)\n\t"
    "s_movk_i32 s20, 0x80\n\t"    // 128 iterations x 4 phases = 512 steps
    "L_lstm_%=:\n\t"
    PHASE("v224", "v195", "v198")   // t%4==0: read A, write B
    PHASE("v225", "v196", "v197")   // t%4==1: read B, write A
    PHASE("v226", "v195", "v198")   // t%4==2: read A, write B
    PHASE("v227", "v196", "v197")   // t%4==3: read B, write A
    "s_sub_u32 s20, s20, 1\n\t"
    "s_cmp_lg_u32 s20, 0\n\t"
    "s_cbranch_scc1 L_lstm_%=\n\t"
    "s_waitcnt vmcnt(0) lgkmcnt(0)\n\t"
    :
    : [xwb]"s"(xwb), [wtb]"s"(Wt), [wto]"v"(wtoff), [xo]"v"(xoff0),
      [rda]"v"(rda), [rdb]"v"(rdb), [wra]"v"(wra), [wrb]"v"(wrb),
      [km]"v"(kmulf), [Aa]"v"(Af), [Bb]"v"(Bf),
      [kodd]"v"(kqodd), [khi]"v"(kqhi)
    : "memory", "scc", "s20", "s22", "s23", "s24", "s25",
      "v32","v33","v34","v35","v36","v37","v38","v39",
      "v40","v41","v42","v43","v44","v45","v46","v47",
      "v64","v65","v66","v67","v68","v69","v70","v71",
      "v72","v73","v74","v75","v76","v77","v78","v79",
      "v80","v81","v82","v83","v84","v85","v86","v87",
      "v88","v89","v90","v91","v92","v93","v94","v95",
      "v96","v97","v98","v99","v100","v101","v102","v103",
      "v104","v105","v106","v107","v108","v109","v110","v111",
      "v112","v113","v114","v115","v116","v117","v118","v119",
      "v120","v121","v122","v123","v124","v125","v126","v127",
      "v194","v195","v196","v197","v198","v199",
      "v200","v201","v202","v203","v204","v205","v206","v207",
      "v208","v209","v210","v211","v212","v213","v214","v215",
      "v216","v217","v218","v219",
      "v224","v225","v226","v227");
  __syncthreads();
  // final h (after t=511) is in buffer A as f16: stripe idx (k>>5)*40 + (k&31)
  if (tid < 4) {
    const __half* hf = (const __half*)hlds;
    float acc = b_fc[tid];
#pragma unroll 8
    for (int k = 0; k < HH; ++k)
      acc = fmaf(__half2float(hf[(k >> 5) * 40 + (k & 31)]), W_fc[k * 4 + tid], acc);
    out[b * 4 + tid] = acc;
  }
}

extern "C" void kernel_launch(void* const* d_in, const int* in_sizes, int n_in,
                              void* d_out, int out_size, void* d_ws, size_t ws_size,
                              hipStream_t stream) {
  const float* x_seq   = (const float*)d_in[0];
  const int*   ei      = (const int*)d_in[1];
  const float* w_gat   = (const float*)d_in[2];
  const float* att_src = (const float*)d_in[3];
  const float* att_dst = (const float*)d_in[4];
  const float* b_gat   = (const float*)d_in[5];
  const float* W_ih    = (const float*)d_in[6];
  const float* W_hh    = (const float*)d_in[7];
  const float* b_ih    = (const float*)d_in[8];
  const float* b_hh    = (const float*)d_in[9];
  const float* W_fc    = (const float*)d_in[10];
  const float* b_fc    = (const float*)d_in[11];

  float* ws = (float*)d_ws;
  float* Wt    = ws;                            // 65536 f16 used (region reserved as 65536 f32)
  float* xw    = Wt + 65536;                    // (16384+8)*512 f (pad rows: 4-deep prefetch)
  float* W_eff = xw + (size_t)(NPOS + 8) * G4;  // 32*512
  float* biasp = W_eff + NN * G4;               // 32*512
  unsigned* flags = (unsigned*)(biasp + NN * G4);  // 32 flags

  prep_kernel<<<NN, G4, 0, stream>>>(w_gat, b_gat, W_ih, W_hh, W_eff, biasp, Wt, flags);
  mega_kernel<<<BB * 9, G4, 0, stream>>>(x_seq, ei, w_gat, att_src, att_dst,
                                         b_ih, b_hh, W_eff, biasp, Wt, W_fc, b_fc,
                                         xw, flags, (float*)d_out);
}